// Round 1
// baseline (602.329 us; speedup 1.0000x reference)
//
#include <hip/hip_runtime.h>

// Fused GRU cell: 5 bf16-MFMA GEMMs + gate epilogue in one kernel.
// Block: 128 rows x 64 cols, BK=32, 256 threads (4 waves), wave tile 32x64.
// 5 accumulator sets per wave (g_ri, g_rh, g_zi, g_ni, g_nh).

#define BM 128
#define BN 64
#define BK 32
#define LDW 40  // BK + 8 pad (bf16 elems) -> 80B row stride, conflict-free b128 reads

typedef __attribute__((ext_vector_type(8))) short  bf16x8;
typedef __attribute__((ext_vector_type(4))) float  f32x4;

__device__ __forceinline__ unsigned short f2bf(float f) {
    union { float f; unsigned u; } v; v.f = f;
    unsigned r = v.u + 0x7FFFu + ((v.u >> 16) & 1u);  // RNE
    return (unsigned short)(r >> 16);
}

__device__ __forceinline__ void stage4(unsigned short* dst, const float4 v) {
    ushort4 u;
    u.x = f2bf(v.x); u.y = f2bf(v.y); u.z = f2bf(v.z); u.w = f2bf(v.w);
    *reinterpret_cast<ushort4*>(dst) = u;  // 8B LDS store
}

__global__ __launch_bounds__(256, 2) void gru_fused(
    const float* __restrict__ input, const float* __restrict__ hidden,
    const float* __restrict__ W_ri, const float* __restrict__ b_ri,
    const float* __restrict__ W_rh, const float* __restrict__ b_rh,
    const float* __restrict__ W_zi, const float* __restrict__ b_zi,
    const float* __restrict__ W_ni, const float* __restrict__ b_ni,
    const float* __restrict__ W_nh, const float* __restrict__ b_nh,
    float* __restrict__ out)
{
    const int H = 1024, K = 1024;
    const int BH = 16384 * 1024;  // one output's element count

    __shared__ __align__(16) unsigned short sIn [BM][LDW];
    __shared__ __align__(16) unsigned short sHid[BM][LDW];
    __shared__ __align__(16) unsigned short sW[5][BN][LDW];

    const int tid  = threadIdx.x;
    const int wave = tid >> 6;
    const int lane = tid & 63;
    const int quad = lane >> 4;   // 0..3
    const int l16  = lane & 15;

    const int row0 = blockIdx.y * BM;   // 128 blocks
    const int col0 = blockIdx.x * BN;   // 16 blocks

    // gate order: 0=r_i(in) 1=r_h(hid) 2=z_i(in) 3=n_i(in) 4=n_h(hid)
    const float* Wg[5] = { W_ri, W_rh, W_zi, W_ni, W_nh };

    f32x4 acc[5][2][4];
    #pragma unroll
    for (int g = 0; g < 5; ++g)
        #pragma unroll
        for (int mi = 0; mi < 2; ++mi)
            #pragma unroll
            for (int ni = 0; ni < 4; ++ni)
                acc[g][mi][ni] = (f32x4){0.f, 0.f, 0.f, 0.f};

    const int sr = tid >> 3;         // 0..31
    const int sc = (tid & 7) << 2;   // 0,4,...,28

    for (int k0 = 0; k0 < K; k0 += BK) {
        __syncthreads();
        // stage input + hidden tiles (128x32 each), fp32->bf16
        #pragma unroll
        for (int p = 0; p < 4; ++p) {
            const int r = p * 32 + sr;
            const float4 vi = *reinterpret_cast<const float4*>(&input [(row0 + r) * K + k0 + sc]);
            const float4 vh = *reinterpret_cast<const float4*>(&hidden[(row0 + r) * K + k0 + sc]);
            stage4(&sIn [r][sc], vi);
            stage4(&sHid[r][sc], vh);
        }
        // stage 5 weight tiles (64x32 each); W is [n][k] row-major already
        #pragma unroll
        for (int g = 0; g < 5; ++g) {
            #pragma unroll
            for (int p = 0; p < 2; ++p) {
                const int idx = p * 256 + tid;   // 0..511
                const int r = idx >> 3;          // 0..63
                const int c = (idx & 7) << 2;
                const float4 v = *reinterpret_cast<const float4*>(&Wg[g][(col0 + r) * K + k0 + c]);
                stage4(&sW[g][r][c], v);
            }
        }
        __syncthreads();

        // A fragments: A[m = l16][k = quad*8 + j]
        bf16x8 aIn[2], aHid[2];
        #pragma unroll
        for (int mi = 0; mi < 2; ++mi) {
            const int r = wave * 32 + mi * 16 + l16;
            aIn [mi] = *reinterpret_cast<const bf16x8*>(&sIn [r][quad * 8]);
            aHid[mi] = *reinterpret_cast<const bf16x8*>(&sHid[r][quad * 8]);
        }
        // B fragments: B[k][n] = W[n][k] -> read sW row n=l16 at k=quad*8
        #pragma unroll
        for (int g = 0; g < 5; ++g) {
            #pragma unroll
            for (int ni = 0; ni < 4; ++ni) {
                const bf16x8 b = *reinterpret_cast<const bf16x8*>(&sW[g][ni * 16 + l16][quad * 8]);
                #pragma unroll
                for (int mi = 0; mi < 2; ++mi) {
                    const bf16x8 a = (g == 1 || g == 4) ? aHid[mi] : aIn[mi];
                    acc[g][mi][ni] = __builtin_amdgcn_mfma_f32_16x16x32_bf16(a, b, acc[g][mi][ni], 0, 0, 0);
                }
            }
        }
    }

    // epilogue: C/D layout row = quad*4 + r4, col = l16 (per 16x16 tile)
    #pragma unroll
    for (int ni = 0; ni < 4; ++ni) {
        const int gcol = col0 + ni * 16 + l16;
        const float bri = b_ri[gcol], brh = b_rh[gcol], bzi = b_zi[gcol];
        const float bni = b_ni[gcol], bnh = b_nh[gcol];
        #pragma unroll
        for (int mi = 0; mi < 2; ++mi) {
            #pragma unroll
            for (int r4 = 0; r4 < 4; ++r4) {
                const int grow = row0 + wave * 32 + mi * 16 + quad * 4 + r4;
                const float g_ri = acc[0][mi][ni][r4];
                const float g_rh = acc[1][mi][ni][r4];
                const float g_zi = acc[2][mi][ni][r4];
                const float g_ni = acc[3][mi][ni][r4];
                const float g_nh = acc[4][mi][ni][r4];
                const float rh = g_rh + brh;                       // reused by r and z (reference bug kept)
                const float rr = 1.f / (1.f + __expf(-(g_ri + bri + rh)));
                const float zz = 1.f / (1.f + __expf(-(g_zi + bzi + rh)));
                const float nn = tanhf(g_ni + bni + rr * (g_nh + bnh));
                const float h  = hidden[grow * H + gcol];          // full fp32 for z*hidden
                const float o  = (1.f - zz) * nn + zz * h;
                out[grow * H + gcol]      = o;
                out[BH + grow * H + gcol] = o;  // tuple returns (h', h')
            }
        }
    }
}

extern "C" void kernel_launch(void* const* d_in, const int* in_sizes, int n_in,
                              void* d_out, int out_size, void* d_ws, size_t ws_size,
                              hipStream_t stream) {
    const float* input = (const float*)d_in[0];
    const float* hidden = (const float*)d_in[1];
    const float* W_ri = (const float*)d_in[2];
    const float* b_ri = (const float*)d_in[3];
    const float* W_rh = (const float*)d_in[4];
    const float* b_rh = (const float*)d_in[5];
    const float* W_zi = (const float*)d_in[6];
    const float* b_zi = (const float*)d_in[7];
    // d_in[8], d_in[9] = W_z_h, b_z_h: dead per the reference's bug (z uses r_h)
    const float* W_ni = (const float*)d_in[10];
    const float* b_ni = (const float*)d_in[11];
    const float* W_nh = (const float*)d_in[12];
    const float* b_nh = (const float*)d_in[13];
    float* out = (float*)d_out;

    dim3 grid(1024 / BN, 16384 / BM);  // (16, 128)
    gru_fused<<<grid, 256, 0, stream>>>(input, hidden,
                                        W_ri, b_ri, W_rh, b_rh,
                                        W_zi, b_zi, W_ni, b_ni,
                                        W_nh, b_nh, out);
}

// Round 2
// 504.638 us; speedup vs baseline: 1.1936x; 1.1936x over previous
//
#include <hip/hip_runtime.h>

// Round 2: two-pass. Pass 1 converts input/hidden/5 weights fp32->bf16 into ws.
// Pass 2: fused 5-GEMM GRU with m97-style global_load_lds(16B) staging of bf16
// tiles (no in-kernel conversion, no VALU ds_writes), MFMA inner loop, fused
// gate epilogue. Block 128x64, BK=32, 4 waves, wave tile 32x64, 5 acc sets.

#define BM 128
#define BN 64
#define BK 32

typedef __attribute__((ext_vector_type(8))) short          bf16x8;
typedef __attribute__((ext_vector_type(8))) unsigned short u16x8;
typedef __attribute__((ext_vector_type(4))) float          f32x4;

__device__ __forceinline__ unsigned short f2bf(float f) {
    union { float f; unsigned u; } v; v.f = f;
    unsigned r = v.u + 0x7FFFu + ((v.u >> 16) & 1u);  // RNE
    return (unsigned short)(r >> 16);
}

// ---- Pass 1: fp32 -> bf16 conversion into ws ----
// ws layout (elements): [0) input 16777216 | [16777216) hidden 16777216 |
//                       [33554432 + g*1048576) W_g for g=0..4
// Elements per vec8 unit; total vec8 = 4,849,664 = 18944 blocks * 256.
__global__ __launch_bounds__(256) void convert_bf16(
    const float* __restrict__ in0, const float* __restrict__ in1,
    const float* __restrict__ w0, const float* __restrict__ w1,
    const float* __restrict__ w2, const float* __restrict__ w3,
    const float* __restrict__ w4, unsigned short* __restrict__ ws)
{
    const long long e = ((long long)blockIdx.x * 256 + threadIdx.x) * 8;
    const float* src;
    if (e < 16777216LL) {
        src = in0 + e;
    } else if (e < 33554432LL) {
        src = in1 + (e - 16777216LL);
    } else {
        const long long t = e - 33554432LL;
        const int g = (int)(t >> 20);
        const long long within = t & 1048575LL;
        const float* w = (g == 0) ? w0 : (g == 1) ? w1 : (g == 2) ? w2 : (g == 3) ? w3 : w4;
        src = w + within;
    }
    const float4 a = *reinterpret_cast<const float4*>(src);
    const float4 b = *reinterpret_cast<const float4*>(src + 4);
    u16x8 o;
    o[0] = f2bf(a.x); o[1] = f2bf(a.y); o[2] = f2bf(a.z); o[3] = f2bf(a.w);
    o[4] = f2bf(b.x); o[5] = f2bf(b.y); o[6] = f2bf(b.z); o[7] = f2bf(b.w);
    *reinterpret_cast<u16x8*>(ws + e) = o;
}

// ---- async 16B global->LDS ----
__device__ __forceinline__ void async16(const void* g, void* l) {
    __builtin_amdgcn_global_load_lds(
        (const __attribute__((address_space(1))) unsigned int*)g,
        (__attribute__((address_space(3))) unsigned int*)l, 16, 0, 0);
}

// ---- Pass 2: fused GRU ----
// LDS staging image (bf16, unpadded -- global_load_lds needs lane-contiguous):
//   [0, 8192)       sIn  [128][32]
//   [8192, 16384)   sHid [128][32]
//   [16384, 36864)  sW[5][64][32]  (4096 B per gate)
// 2304 16B slots; slot s for (j,wave,lane) = (j*4+wave)*64 + lane, j=0..8.
__global__ __launch_bounds__(256, 2) void gru_fused(
    const unsigned short* __restrict__ bf,   // ws: bf16 image
    const float* __restrict__ hidden,        // fp32, for epilogue z*h
    const float* __restrict__ b_ri, const float* __restrict__ b_rh,
    const float* __restrict__ b_zi, const float* __restrict__ b_ni,
    const float* __restrict__ b_nh,
    float* __restrict__ out)
{
    const int H = 1024, K = 1024;
    const int BH = 16384 * 1024;

    __shared__ __align__(16) unsigned char sBuf[36864];

    const int tid  = threadIdx.x;
    const int wave = tid >> 6;
    const int lane = tid & 63;
    const int quad = lane >> 4;
    const int l16  = lane & 15;

    const int row0 = blockIdx.y * BM;
    const int col0 = blockIdx.x * BN;

    const unsigned short* inB  = bf;               // input  bf16 [16384][1024]
    const unsigned short* hidB = bf + 16777216;    // hidden bf16 [16384][1024]
    const unsigned short* wB   = bf + 33554432;    // W bf16 [5][1024][1024]

    // Precompute per-slot global base pointers (at k0=0) and LDS offsets.
    const unsigned short* srcbase[9];
    int ldsoff[9];
    #pragma unroll
    for (int j = 0; j < 9; ++j) {
        const int s = (j * 4 + wave) * 64 + lane;
        ldsoff[j] = s * 16;
        if (s < 512) {                       // input tile: 4 slots per 64B row
            const int r = s >> 2;
            srcbase[j] = inB + (long long)(row0 + r) * K + (s & 3) * 8;
        } else if (s < 1024) {               // hidden tile
            const int r = (s - 512) >> 2;
            srcbase[j] = hidB + (long long)(row0 + r) * K + (s & 3) * 8;
        } else {                             // weight tiles
            const int t = s - 1024;
            const int g = t >> 8;
            const int tt = t & 255;
            const int n = tt >> 2;
            srcbase[j] = wB + (long long)g * 1048576 + (long long)(col0 + n) * K + (tt & 3) * 8;
        }
    }

    f32x4 acc[5][2][4];
    #pragma unroll
    for (int g = 0; g < 5; ++g)
        #pragma unroll
        for (int mi = 0; mi < 2; ++mi)
            #pragma unroll
            for (int ni = 0; ni < 4; ++ni)
                acc[g][mi][ni] = (f32x4){0.f, 0.f, 0.f, 0.f};

    for (int k0 = 0; k0 < K; k0 += BK) {
        __syncthreads();
        #pragma unroll
        for (int j = 0; j < 9; ++j)
            async16(srcbase[j] + k0, sBuf + ldsoff[j]);
        __syncthreads();

        bf16x8 aIn[2], aHid[2];
        #pragma unroll
        for (int mi = 0; mi < 2; ++mi) {
            const int r = wave * 32 + mi * 16 + l16;
            aIn [mi] = *reinterpret_cast<const bf16x8*>(&sBuf[r * 64 + quad * 16]);
            aHid[mi] = *reinterpret_cast<const bf16x8*>(&sBuf[8192 + r * 64 + quad * 16]);
        }
        #pragma unroll
        for (int g = 0; g < 5; ++g) {
            #pragma unroll
            for (int ni = 0; ni < 4; ++ni) {
                const int n = ni * 16 + l16;
                const bf16x8 b = *reinterpret_cast<const bf16x8*>(
                    &sBuf[16384 + g * 4096 + n * 64 + quad * 16]);
                #pragma unroll
                for (int mi = 0; mi < 2; ++mi) {
                    const bf16x8 a = (g == 1 || g == 4) ? aHid[mi] : aIn[mi];
                    acc[g][mi][ni] = __builtin_amdgcn_mfma_f32_16x16x32_bf16(a, b, acc[g][mi][ni], 0, 0, 0);
                }
            }
        }
    }

    // Epilogue: C/D layout row = quad*4 + r4, col = l16 per 16x16 tile.
    #pragma unroll
    for (int ni = 0; ni < 4; ++ni) {
        const int gcol = col0 + ni * 16 + l16;
        const float bri = b_ri[gcol], brh = b_rh[gcol], bzi = b_zi[gcol];
        const float bni = b_ni[gcol], bnh = b_nh[gcol];
        #pragma unroll
        for (int mi = 0; mi < 2; ++mi) {
            #pragma unroll
            for (int r4 = 0; r4 < 4; ++r4) {
                const int grow = row0 + wave * 32 + mi * 16 + quad * 4 + r4;
                const float g_ri = acc[0][mi][ni][r4];
                const float g_rh = acc[1][mi][ni][r4];
                const float g_zi = acc[2][mi][ni][r4];
                const float g_ni = acc[3][mi][ni][r4];
                const float g_nh = acc[4][mi][ni][r4];
                const float rh = g_rh + brh;                  // shared by r and z (reference bug kept)
                const float rr = 1.f / (1.f + __expf(-(g_ri + bri + rh)));
                const float zz = 1.f / (1.f + __expf(-(g_zi + bzi + rh)));
                const float nn = tanhf(g_ni + bni + rr * (g_nh + bnh));
                const float h  = hidden[(long long)grow * H + gcol];
                const float o  = (1.f - zz) * nn + zz * h;
                out[(long long)grow * H + gcol]      = o;
                out[BH + (long long)grow * H + gcol] = o;
            }
        }
    }
}

extern "C" void kernel_launch(void* const* d_in, const int* in_sizes, int n_in,
                              void* d_out, int out_size, void* d_ws, size_t ws_size,
                              hipStream_t stream) {
    const float* input  = (const float*)d_in[0];
    const float* hidden = (const float*)d_in[1];
    const float* W_ri = (const float*)d_in[2];
    const float* b_ri = (const float*)d_in[3];
    const float* W_rh = (const float*)d_in[4];
    const float* b_rh = (const float*)d_in[5];
    const float* W_zi = (const float*)d_in[6];
    const float* b_zi = (const float*)d_in[7];
    // d_in[8], d_in[9] = W_z_h, b_z_h: dead per the reference's bug (z uses r_h)
    const float* W_ni = (const float*)d_in[10];
    const float* b_ni = (const float*)d_in[11];
    const float* W_nh = (const float*)d_in[12];
    const float* b_nh = (const float*)d_in[13];
    float* out = (float*)d_out;
    unsigned short* ws = (unsigned short*)d_ws;

    // gate order in ws: 0=r_i 1=r_h 2=z_i 3=n_i 4=n_h
    convert_bf16<<<18944, 256, 0, stream>>>(input, hidden, W_ri, W_rh, W_zi, W_ni, W_nh, ws);

    dim3 grid(1024 / BN, 16384 / BM);  // (16, 128)
    gru_fused<<<grid, 256, 0, stream>>>(ws, hidden, b_ri, b_rh, b_zi, b_ni, b_nh, out);
}